// Round 1
// baseline (166.670 us; speedup 1.0000x reference)
//
#include <hip/hip_runtime.h>
#include <math.h>

// LSH attention: B=2, H=8, S=2048, D=64, 6 hash bits -> 64 buckets.
// Exact-match bucket attention. 3 phases:
//  1) bucket codes for Q and K (sign of X . rotations, norm dropped: sign-preserving)
//  2) per-(b,h) stable counting sort of key indices by bucket (deterministic)
//  3) wave-per-query gather attention over the matching bucket's key list

constexpr int S_LEN = 2048;
constexpr int D = 64;
constexpr int NHASH = 6;
constexpr int H_HEADS = 8;
constexpr int BH = 16;     // B*H
constexpr int NB = 64;     // 2^NHASH buckets

__device__ __forceinline__ float wave_reduce_sum(float v) {
#pragma unroll
    for (int off = 32; off >= 1; off >>= 1)
        v += __shfl_xor(v, off, 64);
    return v;
}

// One wave per vector (lane = dim). 6 projections -> 6-bit code.
__global__ __launch_bounds__(256) void lsh_buckets(const float* __restrict__ X,
                                                   const float* __restrict__ rot,
                                                   int* __restrict__ buckets) {
    const int wid  = (blockIdx.x * 256 + threadIdx.x) >> 6;   // vector index in [0, BH*S)
    const int lane = threadIdx.x & 63;
    const int h    = (wid >> 11) & (H_HEADS - 1);             // (wid / S) % H, S = 2048
    const float x  = X[(size_t)wid * D + lane];
    const float* r = rot + (size_t)h * NHASH * D + lane;
    int bucket = 0;
#pragma unroll
    for (int n = 0; n < NHASH; ++n) {
        float s = wave_reduce_sum(x * r[n * D]);
        if (s > 0.0f) bucket |= (1 << n);
    }
    if (lane == 0) buckets[wid] = bucket;
}

// One block per (b,h). Stable counting sort of 2048 key indices into 64 buckets.
// Deterministic: per-chunk histograms + serial-per-bucket chunk prefix scan.
__global__ __launch_bounds__(256) void lsh_build_lists(const int* __restrict__ k_buckets,
                                                       int* __restrict__ bucket_start, // [BH][NB+1]
                                                       int* __restrict__ key_list) {   // [BH][S]
    __shared__ unsigned short hist[256][NB + 1];  // [chunk][bucket], +1 pad vs bank conflicts
    __shared__ int base[NB + 1];
    const int bh  = blockIdx.x;
    const int tid = threadIdx.x;
    const int* kb = k_buckets + bh * S_LEN;

    for (int b = 0; b <= NB; ++b) hist[tid][b] = 0;

    int myb[8];                                   // thread tid owns keys [8*tid, 8*tid+8)
#pragma unroll
    for (int i = 0; i < 8; ++i) {
        int b = kb[tid * 8 + i];
        myb[i] = b;
        hist[tid][b]++;
    }
    __syncthreads();

    // bucket t: exclusive prefix over chunks; leaves per-chunk offsets in hist
    if (tid < NB) {
        int run = 0;
        for (int c = 0; c < 256; ++c) {
            int t = hist[c][tid];
            hist[c][tid] = (unsigned short)run;
            run += t;
        }
        base[tid] = run;   // total count for bucket tid (temporarily)
    }
    __syncthreads();

    if (tid == 0) {
        int run = 0;
        for (int b = 0; b < NB; ++b) {
            int t = base[b];
            base[b] = run;
            bucket_start[bh * (NB + 1) + b] = run;
            run += t;
        }
        base[NB] = run;
        bucket_start[bh * (NB + 1) + NB] = run;
    }
    __syncthreads();

    // stable placement: global order == key order
#pragma unroll
    for (int i = 0; i < 8; ++i) {
        int b   = myb[i];
        int ofs = base[b] + hist[tid][b];
        hist[tid][b]++;
        key_list[bh * S_LEN + ofs] = tid * 8 + i;
    }
}

// One wave per query; all control flow wave-uniform. Online softmax over the
// matching bucket's key list only (~32 keys avg).
__global__ __launch_bounds__(256) void lsh_attn(const float* __restrict__ Q,
                                                const float* __restrict__ K,
                                                const float* __restrict__ V,
                                                const int* __restrict__ q_buckets,
                                                const int* __restrict__ bucket_start,
                                                const int* __restrict__ key_list,
                                                float* __restrict__ out) {
    const int wid  = (blockIdx.x * 256 + threadIdx.x) >> 6;   // query index in [0, BH*S)
    const int lane = threadIdx.x & 63;
    const int bh   = wid >> 11;

    const int qb    = q_buckets[wid];
    const int start = bucket_start[bh * (NB + 1) + qb];
    const int end   = bucket_start[bh * (NB + 1) + qb + 1];
    const int* list = key_list + bh * S_LEN;
    const float* Kb = K + (size_t)bh * S_LEN * D;
    const float* Vb = V + (size_t)bh * S_LEN * D;

    const float qv = Q[(size_t)wid * D + lane];

    float m = -INFINITY, l = 0.0f, acc = 0.0f;
    for (int j = start; j < end; ++j) {
        const int k   = list[j];
        const float kv = Kb[k * D + lane];
        const float s  = wave_reduce_sum(qv * kv) * 0.125f;   // 1/sqrt(64)
        const float mn = fmaxf(m, s);
        const float sc = __expf(m - mn);                      // exp(-inf)=0 on first hit
        const float e  = __expf(s - mn);
        l   = l * sc + e;
        acc = acc * sc + e * Vb[k * D + lane];
        m   = mn;
    }
    out[(size_t)wid * D + lane] = acc / (l + 1e-8f) * (1.0f / 6.0f);
}

extern "C" void kernel_launch(void* const* d_in, const int* in_sizes, int n_in,
                              void* d_out, int out_size, void* d_ws, size_t ws_size,
                              hipStream_t stream) {
    const float* Q   = (const float*)d_in[0];
    const float* K   = (const float*)d_in[1];
    const float* V   = (const float*)d_in[2];
    const float* rot = (const float*)d_in[3];
    float* out = (float*)d_out;

    char* ws = (char*)d_ws;
    int* q_buckets    = (int*)(ws);             // 32768 * 4 = 128 KB
    int* k_buckets    = (int*)(ws + 131072);    // 128 KB
    int* bucket_start = (int*)(ws + 262144);    // 16*65*4 = 4160 B (padded to 8 KB)
    int* key_list     = (int*)(ws + 270336);    // 128 KB  -> total ~392 KB

    const int nvec_blocks = BH * S_LEN / 4;     // 4 waves/block, 1 vector/wave
    lsh_buckets<<<nvec_blocks, 256, 0, stream>>>(Q, rot, q_buckets);
    lsh_buckets<<<nvec_blocks, 256, 0, stream>>>(K, rot, k_buckets);
    lsh_build_lists<<<BH, 256, 0, stream>>>(k_buckets, bucket_start, key_list);
    lsh_attn<<<nvec_blocks, 256, 0, stream>>>(Q, K, V, q_buckets, bucket_start, key_list, out);
}

// Round 2
// 154.779 us; speedup vs baseline: 1.0768x; 1.0768x over previous
//
#include <hip/hip_runtime.h>
#include <math.h>

// LSH attention: B=2, H=8, S=2048, D=64, 6 bits -> 64 buckets, exact-match.
// Phase 1: bucket codes for Q and K (fused, sign of X.rot)
// Phase 2: stable counting sort of BOTH query and key indices by bucket
// Phase 3: block per (bh,bucket); stage K^T and V in LDS; waves process
//          queries in lane=key layout (no per-pair reduce), online softmax
//          over 64-key chunks.

constexpr int S_LEN = 2048;
constexpr int D = 64;
constexpr int NHASH = 6;
constexpr int BH = 16;     // B*H
constexpr int NB = 64;     // 2^NHASH

__device__ __forceinline__ float wave_sum(float v) {
#pragma unroll
    for (int off = 32; off >= 1; off >>= 1) v += __shfl_xor(v, off, 64);
    return v;
}
__device__ __forceinline__ float wave_max(float v) {
#pragma unroll
    for (int off = 32; off >= 1; off >>= 1) v = fmaxf(v, __shfl_xor(v, off, 64));
    return v;
}

// ---- Phase 1: bucket codes for Q and K in one dispatch. One wave per vector.
__global__ __launch_bounds__(256) void lsh_buckets2(const float* __restrict__ Q,
                                                    const float* __restrict__ K,
                                                    const float* __restrict__ rot,
                                                    int* __restrict__ qb,
                                                    int* __restrict__ kb) {
    const int gw   = (blockIdx.x * 256 + threadIdx.x) >> 6;  // 0 .. 2*BH*S
    const int lane = threadIdx.x & 63;
    const bool isK = gw >= BH * S_LEN;
    const int wid  = isK ? gw - BH * S_LEN : gw;
    const float* X = isK ? K : Q;
    int* dst       = isK ? kb : qb;
    const int h    = (wid >> 11) & 7;

    const float x  = X[(size_t)wid * D + lane];
    const float* r = rot + (size_t)h * NHASH * D + lane;
    // 6 independent reduction trees (pipelined, not serial)
    float p0 = x * r[0 * D], p1 = x * r[1 * D], p2 = x * r[2 * D];
    float p3 = x * r[3 * D], p4 = x * r[4 * D], p5 = x * r[5 * D];
#pragma unroll
    for (int off = 32; off >= 1; off >>= 1) {
        p0 += __shfl_xor(p0, off, 64);
        p1 += __shfl_xor(p1, off, 64);
        p2 += __shfl_xor(p2, off, 64);
        p3 += __shfl_xor(p3, off, 64);
        p4 += __shfl_xor(p4, off, 64);
        p5 += __shfl_xor(p5, off, 64);
    }
    int bucket = (p0 > 0.f ? 1 : 0) | (p1 > 0.f ? 2 : 0) | (p2 > 0.f ? 4 : 0) |
                 (p3 > 0.f ? 8 : 0) | (p4 > 0.f ? 16 : 0) | (p5 > 0.f ? 32 : 0);
    if (lane == 0) dst[wid] = bucket;
}

// ---- Phase 2: stable counting sort, one block per (which, bh). which: 0=Q 1=K
__global__ __launch_bounds__(256) void lsh_build_lists2(const int* __restrict__ qbuckets,
                                                        const int* __restrict__ kbuckets,
                                                        int* __restrict__ q_start,
                                                        int* __restrict__ q_list,
                                                        int* __restrict__ k_start,
                                                        int* __restrict__ k_list) {
    __shared__ unsigned short hist[256][NB + 1];
    __shared__ int base[NB + 1];
    const int which = blockIdx.x >> 4;
    const int bh    = blockIdx.x & 15;
    const int tid   = threadIdx.x;
    const int* src  = (which ? kbuckets : qbuckets) + bh * S_LEN;
    int* bstart     = (which ? k_start : q_start) + bh * (NB + 1);
    int* blist      = (which ? k_list : q_list) + bh * S_LEN;

    for (int b = 0; b <= NB; ++b) hist[tid][b] = 0;

    int myb[8];
#pragma unroll
    for (int i = 0; i < 8; ++i) {
        int b = src[tid * 8 + i];
        myb[i] = b;
        hist[tid][b]++;
    }
    __syncthreads();

    if (tid < NB) {
        int run = 0;
        for (int c = 0; c < 256; ++c) {
            int t = hist[c][tid];
            hist[c][tid] = (unsigned short)run;
            run += t;
        }
        base[tid] = run;
    }
    __syncthreads();

    if (tid == 0) {
        int run = 0;
        for (int b = 0; b < NB; ++b) {
            int t = base[b];
            base[b] = run;
            bstart[b] = run;
            run += t;
        }
        base[NB] = run;
        bstart[NB] = run;
    }
    __syncthreads();

#pragma unroll
    for (int i = 0; i < 8; ++i) {
        int b   = myb[i];
        int ofs = base[b] + hist[tid][b];
        hist[tid][b]++;
        blist[ofs] = tid * 8 + i;
    }
}

// ---- Phase 3: block per (bh, bucket). 4 waves, 2 queries per wave per pass.
__global__ __launch_bounds__(256) void lsh_attn_bucket(const float* __restrict__ Q,
                                                       const float* __restrict__ K,
                                                       const float* __restrict__ V,
                                                       const int* __restrict__ q_start,
                                                       const int* __restrict__ q_list,
                                                       const int* __restrict__ k_start,
                                                       const int* __restrict__ k_list,
                                                       float* __restrict__ out) {
    const int bh     = blockIdx.x >> 6;
    const int bucket = blockIdx.x & 63;
    const int tid    = threadIdx.x;
    const int wave   = tid >> 6;
    const int lane   = tid & 63;

    const int qs = q_start[bh * (NB + 1) + bucket];
    const int qe = q_start[bh * (NB + 1) + bucket + 1];
    const int ks = k_start[bh * (NB + 1) + bucket];
    const int ke = k_start[bh * (NB + 1) + bucket + 1];
    const int nq = qe - qs, nk = ke - ks;
    if (nq == 0) return;

    const int* ql    = q_list + bh * S_LEN + qs;
    const int* kl    = k_list + bh * S_LEN + ks;
    const float* Qb  = Q + (size_t)bh * S_LEN * D;
    const float* Kb  = K + (size_t)bh * S_LEN * D;
    const float* Vb  = V + (size_t)bh * S_LEN * D;
    float* outb      = out + (size_t)bh * S_LEN * D;

    if (nk == 0) {  // empty key bucket: reference gives all-zero rows
        for (int i = wave; i < nq; i += 4) outb[(size_t)ql[i] * D + lane] = 0.0f;
        return;
    }

    __shared__ float KtI[16][64][4];   // KtI[d4][k][j] = K[k][4*d4+j]
    __shared__ float VtI[16][64][4];   // VtI[k4][d][j] = V[4*k4+j][d]
    __shared__ float wbuf[4][2][64];

    const int nchunks = (nk + 63) >> 6;
    const int npass   = (nq + 7) >> 3;  // 4 waves x 2 queries

    for (int pass = 0; pass < npass; ++pass) {
        const int qi0   = pass * 8 + wave * 2;
        const int qi1   = qi0 + 1;
        const bool v0   = qi0 < nq;
        const bool v1   = qi1 < nq;
        const int qidx0 = v0 ? ql[qi0] : ql[0];
        const int qidx1 = v1 ? ql[qi1] : ql[0];
        const float* qr0 = Qb + (size_t)qidx0 * D;
        const float* qr1 = Qb + (size_t)qidx1 * D;

        float m0 = -INFINITY, l0 = 0.f, acc0 = 0.f;
        float m1 = -INFINITY, l1 = 0.f, acc1 = 0.f;

        for (int c = 0; c < nchunks; ++c) {
            if (nchunks > 1 || pass == 0) {
                __syncthreads();
                {   // stage K chunk, transposed+interleaved
                    const int kk  = tid & 63;
                    const int grp = tid >> 6;
                    const int g   = c * 64 + kk;
                    if (g < nk) {
                        const float* kr = Kb + (size_t)kl[g] * D;
#pragma unroll
                        for (int i = 0; i < 4; ++i) {
                            const int d4 = grp * 4 + i;
                            *(float4*)&KtI[d4][kk][0] = *(const float4*)(kr + d4 * 4);
                        }
                    } else {
#pragma unroll
                        for (int i = 0; i < 4; ++i)
                            *(float4*)&KtI[grp * 4 + i][kk][0] = float4{0, 0, 0, 0};
                    }
                }
                {   // stage V chunk (coalesced global, b32 LDS writes)
#pragma unroll
                    for (int j = 0; j < 16; ++j) {
                        const int r = wave * 16 + j;
                        const int g = c * 64 + r;
                        const float val = (g < nk) ? Vb[(size_t)kl[g] * D + lane] : 0.0f;
                        VtI[r >> 2][lane][r & 3] = val;
                    }
                }
                __syncthreads();
            }

            // ---- scores: lane = key
            float s0 = 0.f, s1 = 0.f;
#pragma unroll
            for (int d4 = 0; d4 < 16; ++d4) {
                const float4 k4 = *(const float4*)&KtI[d4][lane][0];
                const float4 qa = *(const float4*)(qr0 + d4 * 4);
                const float4 qc = *(const float4*)(qr1 + d4 * 4);
                s0 += k4.x * qa.x + k4.y * qa.y + k4.z * qa.z + k4.w * qa.w;
                s1 += k4.x * qc.x + k4.y * qc.y + k4.z * qc.z + k4.w * qc.w;
            }
            s0 *= 0.125f; s1 *= 0.125f;
            const bool kvalid = (c * 64 + lane) < nk;
            if (!kvalid) { s0 = -INFINITY; s1 = -INFINITY; }

            const float cm0 = wave_max(s0), cm1 = wave_max(s1);
            const float mn0 = fmaxf(m0, cm0), mn1 = fmaxf(m1, cm1);
            const float sc0 = __expf(m0 - mn0), sc1 = __expf(m1 - mn1);
            const float e0 = kvalid ? __expf(s0 - mn0) : 0.f;
            const float e1 = kvalid ? __expf(s1 - mn1) : 0.f;
            const float cs0 = wave_sum(e0), cs1 = wave_sum(e1);
            l0 = l0 * sc0 + cs0; m0 = mn0;
            l1 = l1 * sc1 + cs1; m1 = mn1;
            acc0 *= sc0; acc1 *= sc1;

            wbuf[wave][0][lane] = e0;
            wbuf[wave][1][lane] = e1;
            // same-wave LDS RAW: compiler inserts lgkmcnt wait

            // ---- PV: lane = dim
#pragma unroll
            for (int k4 = 0; k4 < 16; ++k4) {
                const float4 v4 = *(const float4*)&VtI[k4][lane][0];
                const float4 wa = *(const float4*)&wbuf[wave][0][k4 * 4];
                const float4 wc = *(const float4*)&wbuf[wave][1][k4 * 4];
                acc0 += wa.x * v4.x + wa.y * v4.y + wa.z * v4.z + wa.w * v4.w;
                acc1 += wc.x * v4.x + wc.y * v4.y + wc.z * v4.z + wc.w * v4.w;
            }
        }

        const float inv6 = 1.0f / 6.0f;
        if (v0) outb[(size_t)qidx0 * D + lane] = acc0 / (l0 + 1e-8f) * inv6;
        if (v1) outb[(size_t)qidx1 * D + lane] = acc1 / (l1 + 1e-8f) * inv6;
    }
}

extern "C" void kernel_launch(void* const* d_in, const int* in_sizes, int n_in,
                              void* d_out, int out_size, void* d_ws, size_t ws_size,
                              hipStream_t stream) {
    const float* Q   = (const float*)d_in[0];
    const float* K   = (const float*)d_in[1];
    const float* V   = (const float*)d_in[2];
    const float* rot = (const float*)d_in[3];
    float* out = (float*)d_out;

    char* ws = (char*)d_ws;
    int* q_buckets = (int*)(ws);              // 128 KB
    int* k_buckets = (int*)(ws + 131072);     // 128 KB
    int* q_start   = (int*)(ws + 262144);     // 8 KB (16*65*4 used)
    int* k_start   = (int*)(ws + 270336);     // 8 KB
    int* q_list    = (int*)(ws + 278528);     // 128 KB
    int* k_list    = (int*)(ws + 409600);     // 128 KB

    lsh_buckets2<<<2 * BH * S_LEN / 4, 256, 0, stream>>>(Q, K, rot, q_buckets, k_buckets);
    lsh_build_lists2<<<32, 256, 0, stream>>>(q_buckets, k_buckets, q_start, q_list, k_start, k_list);
    lsh_attn_bucket<<<BH * NB, 256, 0, stream>>>(Q, K, V, q_start, q_list, k_start, k_list, out);
}